// Round 8
// baseline (836.620 us; speedup 1.0000x reference)
//
#include <hip/hip_runtime.h>

// GraphSAGEConv: out_i = mean_{j in N(i)} x_j @ W_l + b_l + x_i @ W_r
// N=100000, E=1600000, D_in=D_out=64.
//
// 4 dispatches:
//   memset:  bcnt/bfill (8 KB)
//   prep:    convert x->bf16 xh, Wl/Wr->bf16  +  coarse bucket histogram
//            (128-node buckets, per-block LDS hist, 1 global atomic/(blk,bkt))
//   binpass: every block locally scans bcnt -> bucket bases (block 0 publishes
//            gbbase for sage), then groups its edge chunk by bucket and writes
//            packed (src<<8)|(dst&127) line-dense into bucket regions (d_ws).
//   sage_atomic: one block per 128-node bucket:
//            - 128x64 f32 accumulator in LDS (pitch 65 floats: ds_add pattern
//              ~2-way aliasing = free; GEMM read pattern exactly 2-way)
//            - waves process disjoint 64-edge slices (binned read ONCE,
//              coalesced), shfl broadcast, half-wave ushort2 bf16 gathers
//              (2 edges/load), ds_add_f32 accumulation: NO fine sort, no
//              caps, no per-node degree skew
//            - one barrier, then fused dual-GEMM out = [mean|x]@[Wl;Wr]+b
//              via mfma_f32_16x16x32_bf16 (wave = column quadrant)

#define DFEAT 64
#define BSH 7                       // 128 nodes per bucket
#define BUCKN 128
#define MAXB 1024                   // bucket arrays (N <= 131072)
#define ACCP 65                     // LDS acc row pitch in floats

typedef short bf16x8 __attribute__((ext_vector_type(8)));
typedef float f32x4 __attribute__((ext_vector_type(4)));

static __device__ __forceinline__ unsigned short f2bf(float f) {
    unsigned int u = __float_as_uint(f);
    unsigned int r = (u + 0x7FFFu + ((u >> 16) & 1u)) >> 16;   // RNE
    return (unsigned short)r;
}
static __device__ __forceinline__ float bf2f_lo(unsigned int u) {
    return __uint_as_float(u << 16);
}
static __device__ __forceinline__ float bf2f_hi(unsigned int u) {
    return __uint_as_float(u & 0xFFFF0000u);
}
// Workgroup-scope LDS float add -> ds_add_f32 (fire-and-forget, no RMW chain)
static __device__ __forceinline__ void lds_fadd(float* p, float v) {
    __hip_atomic_fetch_add(p, v, __ATOMIC_RELAXED, __HIP_MEMORY_SCOPE_WORKGROUP);
}

// convert (blocks [0, convBlocks)) + coarse histogram (blocks [convBlocks, +256))
__launch_bounds__(256)
__global__ void prep(const float* __restrict__ x,
                     const float* __restrict__ Wl,
                     const float* __restrict__ Wr,
                     const int* __restrict__ dst,
                     unsigned short* __restrict__ xh,
                     unsigned short* __restrict__ wl16,
                     unsigned short* __restrict__ wr16,
                     int* __restrict__ bcnt,
                     int nx4, int convBlocks, int E, int nbuck) {
    __shared__ int h[MAXB];
    int b = blockIdx.x, t = threadIdx.x;
    if (b < convBlocks) {
        int i = b * 256 + t;
        const float* sp; unsigned short* dp; int k;
        if (i < 1024)      { sp = Wl; dp = wl16; k = i; }
        else if (i < 2048) { sp = Wr; dp = wr16; k = i - 1024; }
        else if (i - 2048 < nx4) { sp = x; dp = xh; k = i - 2048; }
        else return;
        float4 v = ((const float4*)sp)[k];
        ushort4 hh;
        hh.x = f2bf(v.x); hh.y = f2bf(v.y); hh.z = f2bf(v.z); hh.w = f2bf(v.w);
        ((ushort4*)dp)[k] = hh;
        return;
    }
    int hb = b - convBlocks;                    // 0..255
    for (int i = t; i < MAXB; i += 256) h[i] = 0;
    __syncthreads();
    int chunk = (E + 255) / 256;
    int lo = hb * chunk;
    int hi = lo + chunk; if (hi > E) hi = E;
    for (int i = lo + t; i < hi; i += 256)
        atomicAdd(&h[((unsigned)dst[i]) >> BSH], 1);
    __syncthreads();
    for (int i = t; i < nbuck; i += 256)
        if (h[i]) atomicAdd(&bcnt[i], h[i]);
}

// Local scan of bcnt -> bases (block 0 publishes gbbase), then bucket-group
// this block's edge chunk and write packed edges line-dense.
__launch_bounds__(256)
__global__ void binpass(const int* __restrict__ src, const int* __restrict__ dst,
                        const int* __restrict__ bcnt, int* __restrict__ bfill,
                        int* __restrict__ gbbase,
                        unsigned int* __restrict__ binned, int E, int nbuck) {
    __shared__ int sA[MAXB], sB[MAXB], ebase[MAXB];
    int t = threadIdx.x;

    // 1024-wide inclusive scan (Hillis-Steele, ping-pong) of bcnt
    for (int i = t; i < MAXB; i += 256) sA[i] = (i < nbuck) ? bcnt[i] : 0;
    __syncthreads();
    int* s = sA; int* d = sB;
    for (int o = 1; o < MAXB; o <<= 1) {
        for (int i = t; i < MAXB; i += 256)
            d[i] = s[i] + ((i >= o) ? s[i - o] : 0);
        __syncthreads();
        int* tmp = s; s = d; d = tmp;
    }
    for (int i = t; i < MAXB; i += 256)
        ebase[i] = (i == 0) ? 0 : s[i - 1];
    if (blockIdx.x == 0) {
        for (int i = t; i < nbuck; i += 256) gbbase[i] = (i == 0) ? 0 : s[i - 1];
        if (t == 0) gbbase[nbuck] = s[nbuck - 1];
    }
    __syncthreads();

    // per-block histogram of its chunk
    int chunk = (E + 255) / 256;                // gridDim.x == 256
    int lo = blockIdx.x * chunk;
    int hi = lo + chunk; if (hi > E) hi = E;
    for (int i = t; i < MAXB; i += 256) sA[i] = 0;
    __syncthreads();
    for (int i = lo + t; i < hi; i += 256)
        atomicAdd(&sA[((unsigned)dst[i]) >> BSH], 1);
    __syncthreads();
    // reserve space per (block,bucket)
    for (int i = t; i < nbuck; i += 256) {
        int c = sA[i];
        sB[i] = c > 0 ? (ebase[i] + atomicAdd(&bfill[i], c)) : 0;
    }
    __syncthreads();
    for (int i = t; i < MAXB; i += 256) sA[i] = 0;
    __syncthreads();
    // place
    for (int i = lo + t; i < hi; i += 256) {
        int dd = dst[i];
        int bu = ((unsigned)dd) >> BSH;
        int p = sB[bu] + atomicAdd(&sA[bu], 1);
        binned[p] = (((unsigned)src[i]) << 8) | ((unsigned)dd & 127u);
    }
}

// Fused atomic-accumulate + dual-GEMM. One block per 128-node bucket.
__launch_bounds__(256)
__global__ void sage_atomic(const unsigned short* __restrict__ xh,
                            const unsigned int* __restrict__ binned,
                            const int* __restrict__ gbbase,
                            const unsigned short* __restrict__ wl16,
                            const unsigned short* __restrict__ wr16,
                            const float* __restrict__ bl,
                            float* __restrict__ out, int N) {
    __shared__ float acc[(BUCKN + 1) * ACCP];   // 129 rows (row 128 = dump)
    __shared__ int cnt[BUCKN + 4];

    int cb = blockIdx.x;
    int n0 = cb << BSH;
    int nn = N - n0; if (nn > BUCKN) nn = BUCKN;

    int t = threadIdx.x;
    int w = t >> 6;
    int lane = t & 63;
    int half = lane >> 5;
    int l2 = lane & 31;

    for (int i = t; i < (BUCKN + 1) * ACCP; i += 256) acc[i] = 0.f;
    if (t < BUCKN + 4) cnt[t] = 0;
    __syncthreads();

    int elo = gbbase[cb], ehi = gbbase[cb + 1];

    // waves process disjoint 64-edge slices; edges read once, coalesced
    for (int base = elo + w * 64; base < ehi; base += 256) {
        int cc = ehi - base; if (cc > 64) cc = 64;
        unsigned int myv = (lane < cc) ? binned[base + lane] : 128u;  // 128 = dump row
        atomicAdd(&cnt[myv & 255u], 1);          // degree: one DS op per chunk
        #pragma unroll
        for (int jb = 0; jb < 32; jb += 8) {
            unsigned int vj[8], rv[8];
            #pragma unroll
            for (int u = 0; u < 8; ++u)
                vj[u] = __shfl(myv, 2 * (jb + u) + half);
            #pragma unroll
            for (int u = 0; u < 8; ++u)
                rv[u] = *(const unsigned int*)(xh + (size_t)(vj[u] >> 8) * DFEAT + l2 * 2);
            #pragma unroll
            for (int u = 0; u < 8; ++u) {
                float* p = &acc[(vj[u] & 255u) * ACCP + l2 * 2];
                lds_fadd(p,     bf2f_lo(rv[u]));
                lds_fadd(p + 1, bf2f_hi(rv[u]));
            }
        }
    }
    __syncthreads();

    // GEMM: wave w = column quadrant nt; 8 row-tiles of 16 nodes
    int nt = w;
    int n15 = lane & 15;
    int quad = lane >> 4;

    bf16x8 bfrag[4];
    #pragma unroll
    for (int kk = 0; kk < 4; ++kk) {
        const unsigned short* W = (kk < 2) ? wl16 : wr16;
        int kbase = (kk & 1) * 32 + quad * 8;
        #pragma unroll
        for (int j = 0; j < 8; ++j)
            bfrag[kk][j] = (short)W[(kbase + j) * DFEAT + nt * 16 + n15];
    }
    float bias = bl[nt * 16 + n15];

    #pragma unroll
    for (int tt = 0; tt < 8; ++tt) {
        if (tt * 16 >= nn) break;
        int lm = tt * 16 + n15;                  // local node row (A row)
        int grow = n0 + lm; if (grow >= N) grow = N - 1;
        float inv = 1.0f / fmaxf((float)cnt[lm], 1.0f);

        bf16x8 a0, a1;
        #pragma unroll
        for (int j = 0; j < 8; ++j) {
            a0[j] = (short)f2bf(acc[lm * ACCP + quad * 8 + j] * inv);
            a1[j] = (short)f2bf(acc[lm * ACCP + 32 + quad * 8 + j] * inv);
        }
        bf16x8 a2 = *(const bf16x8*)(xh + (size_t)grow * DFEAT + quad * 8);
        bf16x8 a3 = *(const bf16x8*)(xh + (size_t)grow * DFEAT + 32 + quad * 8);

        f32x4 c = {0.f, 0.f, 0.f, 0.f};
        c = __builtin_amdgcn_mfma_f32_16x16x32_bf16(a0, bfrag[0], c, 0, 0, 0);
        c = __builtin_amdgcn_mfma_f32_16x16x32_bf16(a1, bfrag[1], c, 0, 0, 0);
        c = __builtin_amdgcn_mfma_f32_16x16x32_bf16(a2, bfrag[2], c, 0, 0, 0);
        c = __builtin_amdgcn_mfma_f32_16x16x32_bf16(a3, bfrag[3], c, 0, 0, 0);

        #pragma unroll
        for (int r = 0; r < 4; ++r) {
            int orow = n0 + tt * 16 + quad * 4 + r;
            if (orow < N)
                out[(size_t)orow * DFEAT + nt * 16 + n15] = c[r] + bias;
        }
    }
}

extern "C" void kernel_launch(void* const* d_in, const int* in_sizes, int n_in,
                              void* d_out, int out_size, void* d_ws, size_t ws_size,
                              hipStream_t stream) {
    const float* x  = (const float*)d_in[0];
    const int*   ei = (const int*)d_in[1];     // [2,E] flat: src then dst
    const float* Wl = (const float*)d_in[2];
    const float* bl = (const float*)d_in[3];
    const float* Wr = (const float*)d_in[4];
    float* out = (float*)d_out;

    const int N = in_sizes[0] / DFEAT;         // 100000
    const int E = in_sizes[1] / 2;             // 1600000
    const int* src = ei;
    const int* dst = ei + E;

    const int nbuck = (N + BUCKN - 1) >> BSH;  // 782

    // ws: [bcnt 1024][bfill 1024][gbbase 1024+16][binned E][wl16][wr16][xh N*64]
    int* ws = (int*)d_ws;
    int* bcnt   = ws;
    int* bfill  = bcnt + MAXB;
    int* gbbase = bfill + MAXB;
    unsigned int* binned = (unsigned int*)(gbbase + MAXB + 16);
    unsigned short* wl16 = (unsigned short*)(binned + E);
    unsigned short* wr16 = wl16 + DFEAT * DFEAT;
    unsigned short* xh   = wr16 + DFEAT * DFEAT;

    hipMemsetAsync(bcnt, 0, 2 * MAXB * sizeof(int), stream);

    int nx4 = N * DFEAT / 4;
    int convBlocks = (2048 + nx4 + 255) / 256;
    prep<<<convBlocks + 256, 256, 0, stream>>>(
        x, Wl, Wr, dst, xh, wl16, wr16, bcnt, nx4, convBlocks, E, nbuck);

    binpass<<<256, 256, 0, stream>>>(src, dst, bcnt, bfill, gbbase, binned, E, nbuck);

    sage_atomic<<<nbuck, 256, 0, stream>>>(
        xh, binned, gbbase, wl16, wr16, bl, out, N);
}

// Round 9
// 225.490 us; speedup vs baseline: 3.7102x; 3.7102x over previous
//
#include <hip/hip_runtime.h>

// GraphSAGEConv: out_i = mean_{j in N(i)} x_j @ W_l + b_l + x_i @ W_r
// N=100000, E=1600000, D_in=D_out=64.
//
// 4 dispatches:
//   memset:  bcnt/bfill (8 KB)
//   prep:    convert x->bf16 xh, Wl/Wr->bf16  +  coarse bucket histogram
//            (128-node buckets, per-block LDS hist, 1 global atomic/(blk,bkt))
//   binpass: 64 blocks x 1024 threads. Each block scans bcnt locally ->
//            bucket bases (block 0 publishes gbbase), then groups its 25k-edge
//            chunk by bucket: ~32-edge (128B) write runs per (block,bucket).
//            Edges packed (src<<8)|(dst&127).
//   sage_fused: ONE block per 128-node bucket (R7 redundancy fixed: each
//            bucket region read once, not 4x):
//            - fine-sort bucket edges into LDS sortbuf (hist+scan+place)
//            - per-wave aggregation: 32 nodes/wave, half-wave ushort2 bf16
//              row gathers (2 edges/load instr), 8-deep ILP, f32 accumulate
//            - means staged bf16 in LDS (72-short pitch, conflict-free)
//            - fused dual-GEMM out = [mean|x]@[Wl;Wr]+b via
//              mfma_f32_16x16x32_bf16 (wave = column quadrant, 8 row-tiles)
//
// NOTE (R8 post-mortem): LDS float atomics (ds_add_rtn_f32) are ~9x slower
// than sort-then-own on gfx950 — serialized returning atomics + waitcnt.

#define DFEAT 64
#define BSH 7                       // 128 nodes per bucket
#define BUCKN 128
#define MAXB 1024                   // bucket arrays (N <= 131072)
#define SORT_CAP 3072               // LDS edge cap (avg 2048, +22 sigma)
#define MLD 72                      // means row pitch in shorts

typedef short bf16x8 __attribute__((ext_vector_type(8)));
typedef float f32x4 __attribute__((ext_vector_type(4)));

static __device__ __forceinline__ unsigned short f2bf(float f) {
    unsigned int u = __float_as_uint(f);
    unsigned int r = (u + 0x7FFFu + ((u >> 16) & 1u)) >> 16;   // RNE
    return (unsigned short)r;
}
static __device__ __forceinline__ float bf2f_lo(unsigned int u) {
    return __uint_as_float(u << 16);
}
static __device__ __forceinline__ float bf2f_hi(unsigned int u) {
    return __uint_as_float(u & 0xFFFF0000u);
}

// convert (blocks [0, convBlocks)) + coarse histogram (blocks [convBlocks, +256))
__launch_bounds__(256)
__global__ void prep(const float* __restrict__ x,
                     const float* __restrict__ Wl,
                     const float* __restrict__ Wr,
                     const int* __restrict__ dst,
                     unsigned short* __restrict__ xh,
                     unsigned short* __restrict__ wl16,
                     unsigned short* __restrict__ wr16,
                     int* __restrict__ bcnt,
                     int nx4, int convBlocks, int E, int nbuck) {
    __shared__ int h[MAXB];
    int b = blockIdx.x, t = threadIdx.x;
    if (b < convBlocks) {
        int i = b * 256 + t;
        const float* sp; unsigned short* dp; int k;
        if (i < 1024)      { sp = Wl; dp = wl16; k = i; }
        else if (i < 2048) { sp = Wr; dp = wr16; k = i - 1024; }
        else if (i - 2048 < nx4) { sp = x; dp = xh; k = i - 2048; }
        else return;
        float4 v = ((const float4*)sp)[k];
        ushort4 hh;
        hh.x = f2bf(v.x); hh.y = f2bf(v.y); hh.z = f2bf(v.z); hh.w = f2bf(v.w);
        ((ushort4*)dp)[k] = hh;
        return;
    }
    int hb = b - convBlocks;                    // 0..255
    for (int i = t; i < MAXB; i += 256) h[i] = 0;
    __syncthreads();
    int chunk = (E + 255) / 256;
    int lo = hb * chunk;
    int hi = lo + chunk; if (hi > E) hi = E;
    for (int i = lo + t; i < hi; i += 256)
        atomicAdd(&h[((unsigned)dst[i]) >> BSH], 1);
    __syncthreads();
    for (int i = t; i < nbuck; i += 256)
        if (h[i]) atomicAdd(&bcnt[i], h[i]);
}

// 64 blocks x 1024 threads. Local scan of bcnt -> bases (block 0 publishes),
// then bucket-group this block's edge chunk; ~32-edge write runs.
__launch_bounds__(1024)
__global__ void binpass(const int* __restrict__ src, const int* __restrict__ dst,
                        const int* __restrict__ bcnt, int* __restrict__ bfill,
                        int* __restrict__ gbbase,
                        unsigned int* __restrict__ binned, int E, int nbuck) {
    __shared__ int sA[MAXB], sB[MAXB], ebase[MAXB];
    int t = threadIdx.x;                        // 0..1023

    // Hillis-Steele inclusive scan of bcnt (one element per thread)
    sA[t] = (t < nbuck) ? bcnt[t] : 0;
    __syncthreads();
    int* s = sA; int* d = sB;
    for (int o = 1; o < MAXB; o <<= 1) {
        d[t] = s[t] + ((t >= o) ? s[t - o] : 0);
        __syncthreads();
        int* tmp = s; s = d; d = tmp;
    }
    ebase[t] = (t == 0) ? 0 : s[t - 1];
    if (blockIdx.x == 0) {
        if (t < nbuck) gbbase[t] = (t == 0) ? 0 : s[t - 1];
        if (t == 0) gbbase[nbuck] = s[nbuck - 1];
    }
    __syncthreads();

    // histogram of this block's chunk
    int nb = gridDim.x;
    int chunk = (E + nb - 1) / nb;
    int lo = blockIdx.x * chunk;
    int hi = lo + chunk; if (hi > E) hi = E;
    sA[t] = 0;
    __syncthreads();
    for (int i = lo + t; i < hi; i += 1024)
        atomicAdd(&sA[((unsigned)dst[i]) >> BSH], 1);
    __syncthreads();
    // reserve space per (block,bucket)
    if (t < nbuck) {
        int c = sA[t];
        sB[t] = c > 0 ? (ebase[t] + atomicAdd(&bfill[t], c)) : 0;
    }
    __syncthreads();
    sA[t] = 0;
    __syncthreads();
    // place
    for (int i = lo + t; i < hi; i += 1024) {
        int dd = dst[i];
        int bu = ((unsigned)dd) >> BSH;
        int p = sB[bu] + atomicAdd(&sA[bu], 1);
        binned[p] = (((unsigned)src[i]) << 8) | ((unsigned)dd & 127u);
    }
}

// Fused fine-sort + aggregate + dual-GEMM. ONE block per 128-node bucket.
__launch_bounds__(256)
__global__ void sage_fused(const unsigned short* __restrict__ xh,
                           const unsigned int* __restrict__ binned,
                           const int* __restrict__ gbbase,
                           const unsigned short* __restrict__ wl16,
                           const unsigned short* __restrict__ wr16,
                           const float* __restrict__ bl,
                           float* __restrict__ out, int N) {
    __shared__ int scnt[BUCKN];
    __shared__ int sbase[BUCKN];
    __shared__ int sfill[BUCKN];
    __shared__ int sx[2][BUCKN];
    __shared__ int sortbuf[SORT_CAP];            // 12 KB
    __shared__ unsigned short means[BUCKN * MLD]; // 18 KB

    int cb = blockIdx.x;
    int n0 = cb << BSH;
    int nn = N - n0; if (nn > BUCKN) nn = BUCKN;

    int t = threadIdx.x;
    int w = t >> 6;
    int lane = t & 63;
    int half = lane >> 5;
    int l2 = lane & 31;

    if (t < BUCKN) { scnt[t] = 0; sfill[t] = 0; }
    __syncthreads();

    int elo = gbbase[cb], ehi = gbbase[cb + 1];

    // fine histogram
    for (int i = elo + t; i < ehi; i += 256)
        atomicAdd(&scnt[binned[i] & 127u], 1);
    __syncthreads();
    // 128-wide exclusive scan
    if (t < BUCKN) sx[0][t] = scnt[t];
    __syncthreads();
    int cur = 0;
    for (int o = 1; o < BUCKN; o <<= 1) {
        if (t < BUCKN) sx[cur ^ 1][t] = sx[cur][t] + ((t >= o) ? sx[cur][t - o] : 0);
        cur ^= 1;
        __syncthreads();
    }
    if (t < BUCKN) sbase[t] = (t == 0) ? 0 : sx[cur][t - 1];
    __syncthreads();
    // place edges into LDS (binned re-read is L2-hot)
    for (int i = elo + t; i < ehi; i += 256) {
        unsigned int v = binned[i];
        int dd = (int)(v & 127u);
        int p = sbase[dd] + atomicAdd(&sfill[dd], 1);
        if (p < SORT_CAP) sortbuf[p] = (int)(v >> 8);
    }
    __syncthreads();

    // aggregation: wave w owns nodes w*32 .. w*32+31
    for (int m = 0; m < 32; ++m) {
        int dd = w * 32 + m;
        if (dd >= nn) break;
        int s0 = sbase[dd];
        int deg = scnt[dd];
        int s1 = s0 + deg; if (s1 > SORT_CAP) s1 = SORT_CAP;

        float2 acc[8];
        #pragma unroll
        for (int u = 0; u < 8; ++u) { acc[u].x = 0.f; acc[u].y = 0.f; }

        for (int base = s0; base < s1; base += 64) {
            int cc = s1 - base; if (cc > 64) cc = 64;
            int myidx = (lane < cc) ? sortbuf[base + lane] : 0;
            int pairs = cc >> 1;
            int ss = 0;
            for (; ss + 8 <= pairs; ss += 8) {
                unsigned int vv[8];
                #pragma unroll
                for (int u = 0; u < 8; ++u) {
                    int id = __shfl(myidx, 2 * (ss + u) + half);
                    vv[u] = *(const unsigned int*)(xh + (size_t)id * DFEAT + l2 * 2);
                }
                #pragma unroll
                for (int u = 0; u < 8; ++u) {
                    acc[u].x += bf2f_lo(vv[u]);
                    acc[u].y += bf2f_hi(vv[u]);
                }
            }
            for (; ss < pairs; ++ss) {
                int id = __shfl(myidx, 2 * ss + half);
                unsigned int v = *(const unsigned int*)(xh + (size_t)id * DFEAT + l2 * 2);
                acc[0].x += bf2f_lo(v);
                acc[0].y += bf2f_hi(v);
            }
            if (cc & 1) {
                int id = __shfl(myidx, cc - 1);
                unsigned int v = *(const unsigned int*)(xh + (size_t)id * DFEAT + l2 * 2);
                if (half == 0) {
                    acc[1].x += bf2f_lo(v);
                    acc[1].y += bf2f_hi(v);
                }
            }
        }

        float2 s2;
        s2.x = ((acc[0].x + acc[1].x) + (acc[2].x + acc[3].x))
             + ((acc[4].x + acc[5].x) + (acc[6].x + acc[7].x));
        s2.y = ((acc[0].y + acc[1].y) + (acc[2].y + acc[3].y))
             + ((acc[4].y + acc[5].y) + (acc[6].y + acc[7].y));
        s2.x += __shfl_xor(s2.x, 32);
        s2.y += __shfl_xor(s2.y, 32);

        if (lane < 32) {
            float inv = 1.0f / fmaxf((float)deg, 1.0f);
            unsigned int pk = (unsigned int)f2bf(s2.x * inv)
                            | ((unsigned int)f2bf(s2.y * inv) << 16);
            *(unsigned int*)&means[dd * MLD + l2 * 2] = pk;
        }
    }
    __syncthreads();

    // GEMM: wave w = column quadrant; 8 row-tiles of 16 nodes
    int nt = w;
    int n15 = lane & 15;
    int quad = lane >> 4;

    bf16x8 bfrag[4];
    #pragma unroll
    for (int kk = 0; kk < 4; ++kk) {
        const unsigned short* W = (kk < 2) ? wl16 : wr16;
        int kbase = (kk & 1) * 32 + quad * 8;
        #pragma unroll
        for (int j = 0; j < 8; ++j)
            bfrag[kk][j] = (short)W[(kbase + j) * DFEAT + nt * 16 + n15];
    }
    float bias = bl[nt * 16 + n15];

    #pragma unroll
    for (int tt = 0; tt < 8; ++tt) {
        if (tt * 16 >= nn) break;
        int m = tt * 16 + n15;                   // local node row (A row)
        int grow = n0 + m; if (grow >= N) grow = N - 1;

        bf16x8 a0 = *(const bf16x8*)&means[m * MLD + quad * 8];
        bf16x8 a1 = *(const bf16x8*)&means[m * MLD + 32 + quad * 8];
        bf16x8 a2 = *(const bf16x8*)(xh + (size_t)grow * DFEAT + quad * 8);
        bf16x8 a3 = *(const bf16x8*)(xh + (size_t)grow * DFEAT + 32 + quad * 8);

        f32x4 c = {0.f, 0.f, 0.f, 0.f};
        c = __builtin_amdgcn_mfma_f32_16x16x32_bf16(a0, bfrag[0], c, 0, 0, 0);
        c = __builtin_amdgcn_mfma_f32_16x16x32_bf16(a1, bfrag[1], c, 0, 0, 0);
        c = __builtin_amdgcn_mfma_f32_16x16x32_bf16(a2, bfrag[2], c, 0, 0, 0);
        c = __builtin_amdgcn_mfma_f32_16x16x32_bf16(a3, bfrag[3], c, 0, 0, 0);

        #pragma unroll
        for (int r = 0; r < 4; ++r) {
            int orow = n0 + tt * 16 + quad * 4 + r;
            if (orow < N)
                out[(size_t)orow * DFEAT + nt * 16 + n15] = c[r] + bias;
        }
    }
}

extern "C" void kernel_launch(void* const* d_in, const int* in_sizes, int n_in,
                              void* d_out, int out_size, void* d_ws, size_t ws_size,
                              hipStream_t stream) {
    const float* x  = (const float*)d_in[0];
    const int*   ei = (const int*)d_in[1];     // [2,E] flat: src then dst
    const float* Wl = (const float*)d_in[2];
    const float* bl = (const float*)d_in[3];
    const float* Wr = (const float*)d_in[4];
    float* out = (float*)d_out;

    const int N = in_sizes[0] / DFEAT;         // 100000
    const int E = in_sizes[1] / 2;             // 1600000
    const int* src = ei;
    const int* dst = ei + E;

    const int nbuck = (N + BUCKN - 1) >> BSH;  // 782

    // ws: [bcnt 1024][bfill 1024][gbbase 1024+16][binned E][wl16][wr16][xh N*64]
    int* ws = (int*)d_ws;
    int* bcnt   = ws;
    int* bfill  = bcnt + MAXB;
    int* gbbase = bfill + MAXB;
    unsigned int* binned = (unsigned int*)(gbbase + MAXB + 16);
    unsigned short* wl16 = (unsigned short*)(binned + E);
    unsigned short* wr16 = wl16 + DFEAT * DFEAT;
    unsigned short* xh   = wr16 + DFEAT * DFEAT;

    hipMemsetAsync(bcnt, 0, 2 * MAXB * sizeof(int), stream);

    int nx4 = N * DFEAT / 4;
    int convBlocks = (2048 + nx4 + 255) / 256;
    prep<<<convBlocks + 256, 256, 0, stream>>>(
        x, Wl, Wr, dst, xh, wl16, wr16, bcnt, nx4, convBlocks, E, nbuck);

    binpass<<<64, 1024, 0, stream>>>(src, dst, bcnt, bfill, gbbase, binned, E, nbuck);

    sage_fused<<<nbuck, 256, 0, stream>>>(
        xh, binned, gbbase, wl16, wr16, bl, out, N);
}

// Round 11
// 207.643 us; speedup vs baseline: 4.0291x; 1.0860x over previous
//
#include <hip/hip_runtime.h>

// GraphSAGEConv: out_i = mean_{j in N(i)} x_j @ W_l + b_l + x_i @ W_r
// N=100000, E=1600000, D_in=D_out=64.
//
// 5 dispatches:
//   memset:   bcnt/bfill (4 KB)
//   prep:     convert x->bf16 xh, Wl/Wr->bf16  +  coarse histogram
//             (256-node buckets, per-block LDS hist, 1 atomic/(blk,bkt))
//   binpass:  64 blocks x 1024 thr. Local scan of bcnt -> bases (block 0
//             publishes gbbase), then bucket-groups its 25k-edge chunk:
//             ~64-edge (256B) line-dense write runs. binned lives in d_out.
//   sortpass: one block per bucket: fine 256-counter LDS hist + scan writes
//             off[] (coalesced) and places sorted_src (16KB-clustered).
//   agg_gemm: 6250 blocks x 16 nodes. Wave w aggregates nodes w*4..w*4+3
//             (R6's best-measured loop: 64-idx coalesced preload, shfl
//             broadcast, half-wave ushort2 bf16 gathers = 2 edges/load,
//             8-deep ILP, f32 accumulate) -> bf16 means in LDS (72-short
//             pitch, R9-verified layout) -> fused dual-GEMM
//             out = [mean|x]@[Wl;Wr]+b via 16 MFMAs (wave = col quadrant).
//
// Post-mortems baked in: LDS float atomics ~9x slower than sort-then-own
// (R8); big-LDS fusion kills occupancy (R9, 33KB -> 27%); global atomics
// cost ~32B memory traffic each (R5); scattered 4B writes cost 64B lines
// (R4); R10 bug: means pitch MUST be >= 64 shorts (row = 64 bf16), k-half
// offset is +32 shorts.

#define DFEAT 64
#define BSHIFT 8                    // 256 nodes per coarse bucket
#define MAXBUCK 512                 // N <= 131072
#define MLD 72                      // means row pitch in shorts (>=64, R9-verified)

typedef short bf16x8 __attribute__((ext_vector_type(8)));
typedef float f32x4 __attribute__((ext_vector_type(4)));

static __device__ __forceinline__ unsigned short f2bf(float f) {
    unsigned int u = __float_as_uint(f);
    unsigned int r = (u + 0x7FFFu + ((u >> 16) & 1u)) >> 16;   // RNE
    return (unsigned short)r;
}
static __device__ __forceinline__ float bf2f_lo(unsigned int u) {
    return __uint_as_float(u << 16);
}
static __device__ __forceinline__ float bf2f_hi(unsigned int u) {
    return __uint_as_float(u & 0xFFFF0000u);
}

// convert (blocks [0, convBlocks)) + coarse histogram (blocks [convBlocks, +256))
__launch_bounds__(256)
__global__ void prep(const float* __restrict__ x,
                     const float* __restrict__ Wl,
                     const float* __restrict__ Wr,
                     const int* __restrict__ dst,
                     unsigned short* __restrict__ xh,
                     unsigned short* __restrict__ wl16,
                     unsigned short* __restrict__ wr16,
                     int* __restrict__ bcnt,
                     int nx4, int convBlocks, int E, int nbuck) {
    __shared__ int h[MAXBUCK];
    int b = blockIdx.x, t = threadIdx.x;
    if (b < convBlocks) {
        int i = b * 256 + t;
        const float* sp; unsigned short* dp; int k;
        if (i < 1024)      { sp = Wl; dp = wl16; k = i; }
        else if (i < 2048) { sp = Wr; dp = wr16; k = i - 1024; }
        else if (i - 2048 < nx4) { sp = x; dp = xh; k = i - 2048; }
        else return;
        float4 v = ((const float4*)sp)[k];
        ushort4 hh;
        hh.x = f2bf(v.x); hh.y = f2bf(v.y); hh.z = f2bf(v.z); hh.w = f2bf(v.w);
        ((ushort4*)dp)[k] = hh;
        return;
    }
    int hb = b - convBlocks;                    // 0..255
    for (int i = t; i < MAXBUCK; i += 256) h[i] = 0;
    __syncthreads();
    int chunk = (E + 255) / 256;
    int lo = hb * chunk;
    int hi = lo + chunk; if (hi > E) hi = E;
    for (int i = lo + t; i < hi; i += 256)
        atomicAdd(&h[((unsigned)dst[i]) >> BSHIFT], 1);
    __syncthreads();
    for (int i = t; i < nbuck; i += 256)
        if (h[i]) atomicAdd(&bcnt[i], h[i]);
}

// 64 blocks x 1024 threads. Local scan of bcnt -> bases (block 0 publishes),
// then bucket-group this block's edge chunk; ~64-edge line-dense write runs.
__launch_bounds__(1024)
__global__ void binpass(const int* __restrict__ src, const int* __restrict__ dst,
                        const int* __restrict__ bcnt, int* __restrict__ bfill,
                        int* __restrict__ gbbase,
                        unsigned int* __restrict__ binned, int E, int nbuck) {
    __shared__ int sA[MAXBUCK], sB[MAXBUCK], ebase[MAXBUCK];
    int t = threadIdx.x;                        // 0..1023

    // 512-wide Hillis-Steele scan of bcnt (threads >=512 idle here)
    if (t < MAXBUCK) sA[t] = (t < nbuck) ? bcnt[t] : 0;
    __syncthreads();
    int* s = sA; int* d = sB;
    for (int o = 1; o < MAXBUCK; o <<= 1) {
        if (t < MAXBUCK) d[t] = s[t] + ((t >= o) ? s[t - o] : 0);
        __syncthreads();
        int* tmp = s; s = d; d = tmp;
    }
    if (t < MAXBUCK) ebase[t] = (t == 0) ? 0 : s[t - 1];
    if (blockIdx.x == 0) {
        if (t < nbuck) gbbase[t] = (t == 0) ? 0 : s[t - 1];
        if (t == 0) gbbase[nbuck] = s[nbuck - 1];
    }
    __syncthreads();

    // histogram of this block's chunk
    int nb = gridDim.x;
    int chunk = (E + nb - 1) / nb;
    int lo = blockIdx.x * chunk;
    int hi = lo + chunk; if (hi > E) hi = E;
    if (t < MAXBUCK) sA[t] = 0;
    __syncthreads();
    for (int i = lo + t; i < hi; i += 1024)
        atomicAdd(&sA[((unsigned)dst[i]) >> BSHIFT], 1);
    __syncthreads();
    if (t < nbuck) {
        int c = sA[t];
        sB[t] = c > 0 ? (ebase[t] + atomicAdd(&bfill[t], c)) : 0;
    }
    __syncthreads();
    if (t < MAXBUCK) sA[t] = 0;
    __syncthreads();
    for (int i = lo + t; i < hi; i += 1024) {
        int dd = dst[i];
        int bu = ((unsigned)dd) >> BSHIFT;
        int p = sB[bu] + atomicAdd(&sA[bu], 1);
        binned[p] = (((unsigned)src[i]) << 8) | ((unsigned)dd & 255u);
    }
}

// One block per 256-node bucket: fine hist + scan -> off[] (coalesced write),
// then place sorted_src (writes land in the bucket's ~16KB region).
__launch_bounds__(256)
__global__ void sortpass(const unsigned int* __restrict__ binned,
                         const int* __restrict__ gbbase,
                         int* __restrict__ off, int* __restrict__ sorted_src,
                         int N, int nbuck) {
    __shared__ int scnt[256];
    __shared__ int sx[2][256];
    __shared__ int sfill[256];
    int b = blockIdx.x, t = threadIdx.x;
    int n0 = b << BSHIFT;
    int nn = N - n0; if (nn > 256) nn = 256;
    scnt[t] = 0; sfill[t] = 0;
    __syncthreads();
    int lo = gbbase[b], hi = gbbase[b + 1];
    for (int i = lo + t; i < hi; i += 256)
        atomicAdd(&scnt[binned[i] & 255u], 1);
    __syncthreads();
    sx[0][t] = scnt[t];
    __syncthreads();
    int cur = 0;
    for (int o = 1; o < 256; o <<= 1) {
        sx[cur ^ 1][t] = sx[cur][t] + ((t >= o) ? sx[cur][t - o] : 0);
        cur ^= 1;
        __syncthreads();
    }
    int myoff = lo + ((t == 0) ? 0 : sx[cur][t - 1]);
    if (t < nn) off[n0 + t] = myoff;
    if (b == nbuck - 1 && t == 0) off[N] = gbbase[nbuck];
    scnt[t] = myoff;                 // reuse as placement base
    __syncthreads();
    for (int i = lo + t; i < hi; i += 256) {
        unsigned int v = binned[i];
        int dd = (int)(v & 255u);
        int p = scnt[dd] + atomicAdd(&sfill[dd], 1);
        sorted_src[p] = (int)(v >> 8);
    }
}

// Fused aggregate + dual-GEMM. One block per 16 nodes; wave w aggregates
// nodes w*4..w*4+3, means staged in 2.3 KB LDS, then wave w = col quadrant.
__launch_bounds__(256)
__global__ void agg_gemm(const unsigned short* __restrict__ xh,
                         const int* __restrict__ sorted_src,
                         const int* __restrict__ off,
                         const unsigned short* __restrict__ wl16,
                         const unsigned short* __restrict__ wr16,
                         const float* __restrict__ bl,
                         float* __restrict__ out, int N) {
    __shared__ unsigned short means[16 * MLD];   // 2304 B

    int t = threadIdx.x;
    int w = t >> 6;
    int lane = t & 63;
    int half = lane >> 5;
    int l2 = lane & 31;
    int n0 = blockIdx.x * 16;

    #pragma unroll
    for (int j = 0; j < 4; ++j) {
        int m = w * 4 + j;
        int node = n0 + m;
        if (node >= N) break;
        int s0 = off[node];
        int s1 = off[node + 1];
        int deg = s1 - s0;

        float2 acc[8];
        #pragma unroll
        for (int u = 0; u < 8; ++u) { acc[u].x = 0.f; acc[u].y = 0.f; }

        for (int base = s0; base < s1; base += 64) {
            int cc = s1 - base; if (cc > 64) cc = 64;
            int myidx = (lane < cc) ? sorted_src[base + lane] : 0;
            int pairs = cc >> 1;
            int ss = 0;
            for (; ss + 8 <= pairs; ss += 8) {
                unsigned int vv[8];
                #pragma unroll
                for (int u = 0; u < 8; ++u) {
                    int id = __shfl(myidx, 2 * (ss + u) + half);
                    vv[u] = *(const unsigned int*)(xh + (size_t)id * DFEAT + l2 * 2);
                }
                #pragma unroll
                for (int u = 0; u < 8; ++u) {
                    acc[u].x += bf2f_lo(vv[u]);
                    acc[u].y += bf2f_hi(vv[u]);
                }
            }
            for (; ss < pairs; ++ss) {
                int id = __shfl(myidx, 2 * ss + half);
                unsigned int v = *(const unsigned int*)(xh + (size_t)id * DFEAT + l2 * 2);
                acc[0].x += bf2f_lo(v);
                acc[0].y += bf2f_hi(v);
            }
            if (cc & 1) {
                int id = __shfl(myidx, cc - 1);
                unsigned int v = *(const unsigned int*)(xh + (size_t)id * DFEAT + l2 * 2);
                if (half == 0) {
                    acc[1].x += bf2f_lo(v);
                    acc[1].y += bf2f_hi(v);
                }
            }
        }

        float2 s2;
        s2.x = ((acc[0].x + acc[1].x) + (acc[2].x + acc[3].x))
             + ((acc[4].x + acc[5].x) + (acc[6].x + acc[7].x));
        s2.y = ((acc[0].y + acc[1].y) + (acc[2].y + acc[3].y))
             + ((acc[4].y + acc[5].y) + (acc[6].y + acc[7].y));
        s2.x += __shfl_xor(s2.x, 32);
        s2.y += __shfl_xor(s2.y, 32);

        if (lane < 32) {
            float inv = 1.0f / fmaxf((float)deg, 1.0f);
            unsigned int pk = (unsigned int)f2bf(s2.x * inv)
                            | ((unsigned int)f2bf(s2.y * inv) << 16);
            *(unsigned int*)&means[m * MLD + l2 * 2] = pk;
        }
    }
    __syncthreads();

    // GEMM: wave w = column quadrant; one 16x16 out tile, K=128
    int nt = w;
    int n15 = lane & 15;
    int quad = lane >> 4;

    bf16x8 bfrag[4];
    #pragma unroll
    for (int kk = 0; kk < 4; ++kk) {
        const unsigned short* W = (kk < 2) ? wl16 : wr16;
        int kbase = (kk & 1) * 32 + quad * 8;
        #pragma unroll
        for (int j = 0; j < 8; ++j)
            bfrag[kk][j] = (short)W[(kbase + j) * DFEAT + nt * 16 + n15];
    }
    float bias = bl[nt * 16 + n15];

    int grow = n0 + n15; if (grow >= N) grow = N - 1;
    bf16x8 a0 = *(const bf16x8*)&means[n15 * MLD + quad * 8];
    bf16x8 a1 = *(const bf16x8*)&means[n15 * MLD + 32 + quad * 8];
    bf16x8 a2 = *(const bf16x8*)(xh + (size_t)grow * DFEAT + quad * 8);
    bf16x8 a3 = *(const bf16x8*)(xh + (size_t)grow * DFEAT + 32 + quad * 8);

    f32x4 c = {0.f, 0.f, 0.f, 0.f};
    c = __builtin_amdgcn_mfma_f32_16x16x32_bf16(a0, bfrag[0], c, 0, 0, 0);
    c = __builtin_amdgcn_mfma_f32_16x16x32_bf16(a1, bfrag[1], c, 0, 0, 0);
    c = __builtin_amdgcn_mfma_f32_16x16x32_bf16(a2, bfrag[2], c, 0, 0, 0);
    c = __builtin_amdgcn_mfma_f32_16x16x32_bf16(a3, bfrag[3], c, 0, 0, 0);

    #pragma unroll
    for (int r = 0; r < 4; ++r) {
        int orow = n0 + quad * 4 + r;
        if (orow < N)
            out[(size_t)orow * DFEAT + nt * 16 + n15] = c[r] + bias;
    }
}

extern "C" void kernel_launch(void* const* d_in, const int* in_sizes, int n_in,
                              void* d_out, int out_size, void* d_ws, size_t ws_size,
                              hipStream_t stream) {
    const float* x  = (const float*)d_in[0];
    const int*   ei = (const int*)d_in[1];     // [2,E] flat: src then dst
    const float* Wl = (const float*)d_in[2];
    const float* bl = (const float*)d_in[3];
    const float* Wr = (const float*)d_in[4];
    float* out = (float*)d_out;

    const int N = in_sizes[0] / DFEAT;         // 100000
    const int E = in_sizes[1] / 2;             // 1600000
    const int* src = ei;
    const int* dst = ei + E;

    const int nbuck = (N + 255) >> BSHIFT;     // 391

    // ws: [bcnt 512][bfill 512][gbbase 528][off N+16][sorted_src E][wl16][wr16][xh N*64]
    int* ws = (int*)d_ws;
    int* bcnt       = ws;
    int* bfill      = bcnt + MAXBUCK;
    int* gbbase     = bfill + MAXBUCK;
    int* off        = gbbase + MAXBUCK + 16;
    int* sorted_src = off + N + 16;
    unsigned short* wl16 = (unsigned short*)(sorted_src + E);
    unsigned short* wr16 = wl16 + DFEAT * DFEAT;
    unsigned short* xh   = wr16 + DFEAT * DFEAT;

    unsigned int* binned = (unsigned int*)d_out;   // consumed before agg_gemm

    hipMemsetAsync(bcnt, 0, 2 * MAXBUCK * sizeof(int), stream);

    int nx4 = N * DFEAT / 4;
    int convBlocks = (2048 + nx4 + 255) / 256;
    prep<<<convBlocks + 256, 256, 0, stream>>>(
        x, Wl, Wr, dst, xh, wl16, wr16, bcnt, nx4, convBlocks, E, nbuck);

    binpass<<<64, 1024, 0, stream>>>(src, dst, bcnt, bfill, gbbase, binned, E, nbuck);
    sortpass<<<nbuck, 256, 0, stream>>>(binned, gbbase, off, sorted_src, N, nbuck);

    agg_gemm<<<(N + 15) / 16, 256, 0, stream>>>(
        xh, sorted_src, off, wl16, wr16, bl, out, N);
}